// Round 6
// baseline (187.618 us; speedup 1.0000x reference)
//
#include <hip/hip_runtime.h>
#include <hip/hip_bf16.h>

#define BB 8
#define NN 2048
#define CC 320
#define CQ 64
#define LOG2E 1.4426950408889634f

typedef __attribute__((ext_vector_type(8)))  short bf16x8;
typedef __attribute__((ext_vector_type(4)))  float f32x4;
typedef __attribute__((ext_vector_type(16))) float f32x16;
typedef __attribute__((ext_vector_type(4)))  unsigned short us4;
typedef __attribute__((ext_vector_type(8)))  unsigned short us8;
typedef __attribute__((ext_vector_type(4)))  unsigned int u32x4;
typedef unsigned short u16;

static __device__ __forceinline__ u16 f2b(float f) {
  unsigned u = __builtin_bit_cast(unsigned, f);
  unsigned r = (u + 0x7FFFu + ((u >> 16) & 1u)) >> 16;
  return (u16)r;
}
static __device__ __forceinline__ float b2f(u16 s) {
  unsigned u = ((unsigned)s) << 16;
  return __builtin_bit_cast(float, u);
}

static __device__ __forceinline__ f32x16 zero16() {
  f32x16 v = {0,0,0,0, 0,0,0,0, 0,0,0,0, 0,0,0,0};
  return v;
}
static __device__ __forceinline__ f32x4 zero4() {
  f32x4 v = {0,0,0,0};
  return v;
}

// ---------------------------------------------------------------------------
// K0a: x fp32 -> xb bf16. grid 5120 x 256
// ---------------------------------------------------------------------------
__global__ __launch_bounds__(256) void cvt_x(const float* __restrict__ x,
                                             u16* __restrict__ xb) {
  const size_t i = (size_t)blockIdx.x * 256 + threadIdx.x;
  float4 v = *(const float4*)(x + i * 4);
  us4 o;
  o.x = f2b(v.x); o.y = f2b(v.y); o.z = f2b(v.z); o.w = f2b(v.w);
  *(us4*)(xb + i * 4) = o;
}

// ---------------------------------------------------------------------------
// K0b: Wq/Wk/Wv fp32 -> concat Wb[448][320] bf16. grid 140 x 256
// ---------------------------------------------------------------------------
__global__ __launch_bounds__(256) void cvt_w(const float* __restrict__ Wq,
                                             const float* __restrict__ Wk,
                                             const float* __restrict__ Wv,
                                             u16* __restrict__ Wb) {
  const int i = blockIdx.x * 256 + threadIdx.x;
  const int idx4 = i * 4;
  const int row = idx4 / CC;
  const int col = idx4 - row * CC;
  const float* src = (row < 64) ? (Wq + (size_t)row * CC)
                   : (row < 128) ? (Wk + (size_t)(row - 64) * CC)
                                 : (Wv + (size_t)(row - 128) * CC);
  float4 v = *(const float4*)(src + col);
  us4 o;
  o.x = f2b(v.x); o.y = f2b(v.y); o.z = f2b(v.z); o.w = f2b(v.w);
  *(us4*)(Wb + (size_t)row * CC + col) = o;
}

// ---------------------------------------------------------------------------
// K1: QKV GEMM. grid (7, 128). x=0: Q cols (scaled by log2e), x=1: K cols,
// x>=2: V cols written transposed into Vt[b][c][n].
// ---------------------------------------------------------------------------
__global__ __launch_bounds__(256) void gemm_qkv(
    const u16* __restrict__ xb, const u16* __restrict__ Wb,
    const float* __restrict__ bq, const float* __restrict__ bk,
    const float* __restrict__ bv,
    u16* __restrict__ Qb, u16* __restrict__ Kb, u16* __restrict__ Vt) {
  const int tid = threadIdx.x;
  const int lane = tid & 63, wid = tid >> 6;
  const int r = lane & 31, h = lane >> 5;
  const int m0 = blockIdx.y * 128 + wid * 32;
  const int col0 = blockIdx.x * 64;

  f32x16 acc0 = zero16(), acc1 = zero16();
  const u16* xrow = xb + (size_t)(m0 + r) * CC + h * 8;
  const u16* w0 = Wb + (size_t)(col0 + r) * CC + h * 8;
  const u16* w1 = w0 + 32 * CC;

  bf16x8 a   = *(const bf16x8*)(xrow);
  bf16x8 b0v = *(const bf16x8*)(w0);
  bf16x8 b1v = *(const bf16x8*)(w1);
#pragma unroll 1
  for (int ks = 0; ks < 20; ++ks) {
    bf16x8 na, nb0, nb1;
    if (ks < 19) {
      na  = *(const bf16x8*)(xrow + (ks + 1) * 16);
      nb0 = *(const bf16x8*)(w0 + (ks + 1) * 16);
      nb1 = *(const bf16x8*)(w1 + (ks + 1) * 16);
    }
    acc0 = __builtin_amdgcn_mfma_f32_32x32x16_bf16(a, b0v, acc0, 0, 0, 0);
    acc1 = __builtin_amdgcn_mfma_f32_32x32x16_bf16(a, b1v, acc1, 0, 0, 0);
    a = na; b0v = nb0; b1v = nb1;
  }

  const int bb = m0 >> 11;        // batch
  const int mloc = m0 & 2047;     // n within batch

#pragma unroll
  for (int nt = 0; nt < 2; ++nt) {
    const int col = col0 + nt * 32 + r;
    const f32x16 A = nt ? acc1 : acc0;
    if (col0 >= 128) {
      // V block: write transposed Vt[(bb*CC + c)][n], packed 4-n us4 stores
      const int c = col - 128;
      const float bias = bv[c];
      u16* vb = Vt + (((size_t)(bb * CC + c)) << 11) + mloc + 4 * h;
#pragma unroll
      for (int g = 0; g < 4; ++g) {
        us4 o;
#pragma unroll
        for (int e = 0; e < 4; ++e) o[e] = f2b(A[g * 4 + e] + bias);
        *(us4*)(vb + g * 8) = o;
      }
    } else if (col0 >= 64) {
      const float bias = bk[col - 64];
#pragma unroll
      for (int reg = 0; reg < 16; ++reg) {
        const int row = m0 + (reg & 3) + 8 * (reg >> 2) + 4 * h;
        Kb[(size_t)row * CQ + (col - 64)] = f2b(A[reg] + bias);
      }
    } else {
      // Q block: fold log2(e) so softmax exp becomes a single v_exp_f32
      const float bias = bq[col];
#pragma unroll
      for (int reg = 0; reg < 16; ++reg) {
        const int row = m0 + (reg & 3) + 8 * (reg >> 2) + 4 * h;
        Qb[(size_t)row * CQ + col] = f2b((A[reg] + bias) * LOG2E);
      }
    }
  }
}

// ---------------------------------------------------------------------------
// K3: row sums + fold 1/S into V.
// S[k] = sum_m 2^(Q'[k]·K[m]); then Vt[b][c][k] *= 1/S[k] for all c.
// Block = 64 k-rows of one batch; 4 waves cover m in 512-chunks. grid 256.
// ---------------------------------------------------------------------------
__global__ __launch_bounds__(256) void row_stats(
    const u16* __restrict__ Qb, const u16* __restrict__ Kb,
    u16* __restrict__ Vt) {
  __shared__ float Sp[4][64];
  __shared__ float sInv[64];
  const int tid = threadIdx.x;
  const int lane = tid & 63, wid = tid >> 6;
  const int rl = lane & 15, hq = lane >> 4;
  const int bid = blockIdx.x;
  const int batch = bid & 7;
  const int r0g = batch * NN + (bid >> 3) * 64;

  bf16x8 af[4][2];
#pragma unroll
  for (int mt = 0; mt < 4; ++mt)
#pragma unroll
    for (int qs = 0; qs < 2; ++qs)
      af[mt][qs] = *(const bf16x8*)(Qb + (size_t)(r0g + mt * 16 + rl) * CQ + qs * 32 + hq * 8);

  float S[4][4];
#pragma unroll
  for (int mt = 0; mt < 4; ++mt)
#pragma unroll
    for (int rr = 0; rr < 4; ++rr) S[mt][rr] = 0.f;

  const int mstart = batch * NN + wid * 512;
  const u16* kr = Kb + (size_t)(mstart + rl) * CQ + hq * 8;
  bf16x8 c0 = *(const bf16x8*)(kr);
  bf16x8 c1 = *(const bf16x8*)(kr + 32);
#pragma unroll 1
  for (int ms = 0; ms < 32; ++ms) {
    bf16x8 n0, n1;
    if (ms < 31) {
      n0 = *(const bf16x8*)(kr + 16 * CQ);
      n1 = *(const bf16x8*)(kr + 16 * CQ + 32);
    }
#pragma unroll
    for (int mt = 0; mt < 4; ++mt) {
      f32x4 e = zero4();
      e = __builtin_amdgcn_mfma_f32_16x16x32_bf16(af[mt][0], c0, e, 0, 0, 0);
      e = __builtin_amdgcn_mfma_f32_16x16x32_bf16(af[mt][1], c1, e, 0, 0, 0);
#pragma unroll
      for (int rr = 0; rr < 4; ++rr) S[mt][rr] += __builtin_amdgcn_exp2f(e[rr]);
    }
    c0 = n0; c1 = n1; kr += 16 * CQ;
  }

#pragma unroll
  for (int d = 1; d < 16; d <<= 1)
#pragma unroll
    for (int mt = 0; mt < 4; ++mt)
#pragma unroll
      for (int rr = 0; rr < 4; ++rr) S[mt][rr] += __shfl_xor(S[mt][rr], d, 64);

  if (rl == 0) {
#pragma unroll
    for (int mt = 0; mt < 4; ++mt)
#pragma unroll
      for (int rr = 0; rr < 4; ++rr) Sp[wid][mt * 16 + hq * 4 + rr] = S[mt][rr];
  }
  __syncthreads();
  if (tid < 64) {
    const float s = Sp[0][tid] + Sp[1][tid] + Sp[2][tid] + Sp[3][tid];
    sInv[tid] = 1.0f / s;
  }
  __syncthreads();

  // scale Vt[b][c][kloc..kloc+64) by sInv — disjoint k-slices across blocks
  const int kloc = (bid >> 3) * 64;
  u16* vp = Vt + (((size_t)(batch * CC)) << 11) + kloc;
#pragma unroll 1
  for (int i = 0; i < 20; ++i) {
    const int chunk = i * 256 + tid;        // 0..5119
    const int c = chunk >> 4;               // 0..319
    const int off = (chunk & 15) * 4;       // 0..60
    u16* p = vp + (((size_t)c) << 11) + off;
    us4 v = *(const us4*)p;
    us4 o;
#pragma unroll
    for (int e2 = 0; e2 < 4; ++e2) o[e2] = f2b(b2f(v[e2]) * sInv[off + e2]);
    *(us4*)p = o;
  }
}

// ---------------------------------------------------------------------------
// K4: attention v4 — barrier-free, LDS-free, one independent wave per
// (batch, 32-row n-tile, 160-col c-half). grid 1024 x 64, batch = bid&7.
// Per 32-k tile: E'[k][n] = mfma(Q'rows, Krows) (n = lane); P = 2^E';
// cvt_pk_bf16 + permlane32_swap assemble PV A-frags IN REGISTERS;
// PV B-frags stream from L2-resident, pre-scaled Vt. Loads prefetched one
// tile ahead (q issued before v -> monotone vmcnt, no drains).
// ---------------------------------------------------------------------------
__global__ __launch_bounds__(64) void attn(
    const u16* __restrict__ Qb, const u16* __restrict__ Kb,
    const u16* __restrict__ Vt, const u16* __restrict__ xb,
    const float* __restrict__ gamma, float* __restrict__ out) {
  const int lane = threadIdx.x;
  const int r = lane & 31, h = lane >> 5;
  const int bid = blockIdx.x;
  const int b = bid & 7;
  const int rest = bid >> 3;
  const int ch = rest & 1;
  const int n0 = (rest >> 1) * 32;

  // K fragments for this n-tile (B operand of E', held all k)
  bf16x8 kf[4];
  {
    const u16* krow = Kb + (size_t)(b * NN + n0 + r) * CQ + h * 8;
#pragma unroll
    for (int qs = 0; qs < 4; ++qs) kf[qs] = *(const bf16x8*)(krow + qs * 16);
  }

  f32x16 acc[5];
#pragma unroll
  for (int j = 0; j < 5; ++j) acc[j] = zero16();

  const u16* qrow = Qb + (size_t)(b * NN + r) * CQ + h * 8;
  const u16* vbase = Vt + (((size_t)(b * CC + ch * 160 + r)) << 11) + h * 8;

  bf16x8 qf[4];
  bf16x8 vf[5][2];
#pragma unroll
  for (int qs = 0; qs < 4; ++qs) qf[qs] = *(const bf16x8*)(qrow + qs * 16);
#pragma unroll
  for (int j = 0; j < 5; ++j)
#pragma unroll
    for (int ks = 0; ks < 2; ++ks)
      vf[j][ks] = *(const bf16x8*)(vbase + (((size_t)(j * 32)) << 11) + ks * 16);

#pragma unroll 1
  for (int t = 0; t < 64; ++t) {
    const int k0n = ((t + 1) & 63) * 32;   // wraps at end (harmless reload)
    // E'(t): rows = k (regs), cols = n (lane)
    f32x16 e = zero16();
#pragma unroll
    for (int qs = 0; qs < 4; ++qs)
      e = __builtin_amdgcn_mfma_f32_32x32x16_bf16(qf[qs], kf[qs], e, 0, 0, 0);
    // prefetch q(t+1) (qf dead after ET)
#pragma unroll
    for (int qs = 0; qs < 4; ++qs)
      qf[qs] = *(const bf16x8*)(qrow + (size_t)k0n * CQ + qs * 16);
    // P = 2^E' -> bf16 pairs -> half-wave swap -> A-frags
    unsigned pk0, pk1, pk2, pk3, pk4, pk5, pk6, pk7;
#define CVT(D, I) { float lo_ = __builtin_amdgcn_exp2f(e[2*(I)]);              \
                    float hi_ = __builtin_amdgcn_exp2f(e[2*(I)+1]);            \
                    asm("v_cvt_pk_bf16_f32 %0, %1, %2"                          \
                        : "=v"(D) : "v"(lo_), "v"(hi_)); }
    CVT(pk0, 0) CVT(pk1, 1) CVT(pk2, 2) CVT(pk3, 3)
    CVT(pk4, 4) CVT(pk5, 5) CVT(pk6, 6) CVT(pk7, 7)
#undef CVT
    asm("v_permlane32_swap_b32 %0, %1" : "+v"(pk0), "+v"(pk2));
    asm("v_permlane32_swap_b32 %0, %1" : "+v"(pk1), "+v"(pk3));
    asm("v_permlane32_swap_b32 %0, %1" : "+v"(pk4), "+v"(pk6));
    asm("v_permlane32_swap_b32 %0, %1" : "+v"(pk5), "+v"(pk7));
    u32x4 w0 = {pk0, pk1, pk2, pk3};
    u32x4 w1 = {pk4, pk5, pk6, pk7};
    bf16x8 pa0 = __builtin_bit_cast(bf16x8, w0);
    bf16x8 pa1 = __builtin_bit_cast(bf16x8, w1);
    // PV(t)
#pragma unroll
    for (int j = 0; j < 5; ++j) {
      acc[j] = __builtin_amdgcn_mfma_f32_32x32x16_bf16(pa0, vf[j][0], acc[j], 0, 0, 0);
      acc[j] = __builtin_amdgcn_mfma_f32_32x32x16_bf16(pa1, vf[j][1], acc[j], 0, 0, 0);
    }
    // prefetch v(t+1) (vf dead after PV)
#pragma unroll
    for (int j = 0; j < 5; ++j)
#pragma unroll
      for (int ks = 0; ks < 2; ++ks)
        vf[j][ks] = *(const bf16x8*)(vbase + (((size_t)(j * 32)) << 11) + k0n + ks * 16);
  }

  const float g = gamma[0];
#pragma unroll
  for (int reg = 0; reg < 16; ++reg) {
    const int nl = n0 + (reg & 3) + 8 * (reg >> 2) + 4 * h;
    const size_t rowb = ((size_t)(b * NN) + nl) * CC + ch * 160 + r;
#pragma unroll
    for (int j = 0; j < 5; ++j) {
      const size_t idx = rowb + (size_t)(j * 32);
      out[idx] = g * acc[j][reg] + b2f(xb[idx]);
    }
  }
}

extern "C" void kernel_launch(void* const* d_in, const int* in_sizes, int n_in,
                              void* d_out, int out_size, void* d_ws, size_t ws_size,
                              hipStream_t stream) {
  const float* x     = (const float*)d_in[0];
  const float* Wq    = (const float*)d_in[1];
  const float* bq    = (const float*)d_in[2];
  const float* Wk    = (const float*)d_in[3];
  const float* bk    = (const float*)d_in[4];
  const float* Wv    = (const float*)d_in[5];
  const float* bv    = (const float*)d_in[6];
  const float* gamma = (const float*)d_in[7];
  float* out = (float*)d_out;

  char* w = (char*)d_ws;
  u16* xb = (u16*)(w);                         // 16384*320  (10485760 B)
  u16* Wb = (u16*)(w + 10485760);              // 448*320    (286720 B)
  u16* Qb = (u16*)(w + 10772480);              // 16384*64   (2097152 B)
  u16* Kb = (u16*)(w + 12869632);              // 16384*64   (2097152 B)
  u16* Vt = (u16*)(w + 14966784);              // 8*320*2048 (10485760 B)

  cvt_x<<<5120, 256, 0, stream>>>(x, xb);
  cvt_w<<<140, 256, 0, stream>>>(Wq, Wk, Wv, Wb);
  gemm_qkv<<<dim3(7, 128), 256, 0, stream>>>(xb, Wb, bq, bk, bv, Qb, Kb, Vt);
  row_stats<<<256, 256, 0, stream>>>(Qb, Kb, Vt);
  attn<<<1024, 64, 0, stream>>>(Qb, Kb, Vt, xb, gamma, out);
}